// Round 3
// baseline (639.957 us; speedup 1.0000x reference)
//
#include <hip/hip_runtime.h>

#define SIZE 1024
#define MM 10
#define NTERMS 10
#define RPB 8          // batch rows resident per block
#define NTHREADS 256   // 128 col-threads x 2 row-sets
#define W 8            // columns per thread
#define RPT 4          // rows per thread (RPB / 2 row-sets)

typedef __attribute__((ext_vector_type(8))) _Float16 h8;   // 16B: ds_read_b128
typedef __attribute__((ext_vector_type(4))) _Float16 h4;   // 8B

__device__ __forceinline__ float4 ldq(const float* p) { return *(const float4*)p; }

// load 8 consecutive floats, scale by s -> w[0..7]
__device__ __forceinline__ void ldw8(const float* p, float s, float* w) {
    const float4 a = ldq(p);
    const float4 b = ldq(p + 4);
    w[0] = s * a.x; w[1] = s * a.y; w[2] = s * a.z; w[3] = s * a.w;
    w[4] = s * b.x; w[5] = s * b.y; w[6] = s * b.z; w[7] = s * b.w;
}

// ---------------------------------------------------------------------------
// fp16-in-LDS butterfly, register-budgeted. vs round 2 (which spilled 168 coef
// regs against a 128-VGPR allocation -> 659MB scratch FETCH):
//  * 4 rows/thread (acc[4][8]=32 regs), RPB=8, 32KB LDS -> 4 blocks/CU.
//  * term split into 3 passes, <=40 coef regs live at a time:
//      0a: diag + d=1 + d=2   (reads c,L,R; pins c)
//      0b: d=4 + d=8          (re-reads L,R; uses pinned c)
//      1 : d=512..16, one j at a time, loop ROLLED so nothing hoists
//  * per-element FMA order identical to round 2 -> bitwise-same output.
// LDS ops/row-octet: 17 reads + 1 write. All arithmetic fp32; only the 9
// inter-term snapshots + initial staging round to fp16 (RTN).
// ---------------------------------------------------------------------------
__global__ __launch_bounds__(NTHREADS, 4)   // pin <=128 VGPR, 16 waves/CU
void butterfly_h16(const float* __restrict__ x,
                   const float* __restrict__ diag,
                   const float* __restrict__ subpad,
                   const float* __restrict__ suppad,
                   const float* __restrict__ logit,
                   float* __restrict__ out)
{
    __shared__ _Float16 buf[2][RPB][SIZE];   // 2*8*1024*2B = 32 KB

    const int tid = threadIdx.x;
    const int ct  = tid & 127;        // column group: cols [8*ct, 8*ct+8)
    const int rs  = tid >> 7;         // row set: rows [4*rs, 4*rs+4)
    const int s0  = ct * W;
    const int r0  = rs * RPT;
    const long rowbase = (long)blockIdx.x * RPB;

    // ---- stage x: fp32 global -> fp16 LDS (coalesced, RTN cvt) ----
    {
        const int sc = tid * 4;       // 256 threads x 4 cols = 1024
        #pragma unroll
        for (int r = 0; r < RPB; ++r) {
            const float4 v = ldq(x + (rowbase + r) * SIZE + sc);
            h4 h;
            h[0] = (_Float16)v.x; h[1] = (_Float16)v.y;
            h[2] = (_Float16)v.z; h[3] = (_Float16)v.w;
            *(h4*)&buf[0][r][sc] = h;
        }
    }
    __syncthreads();

    int cur = 0;
    for (int t = 0; t < NTERMS; ++t) {
        const int i = NTERMS - 1 - t;     // reference applies prob[9] first

        // ---- softmax over logit[i][:] -> lg[j] = p_j (static-indexed regs) ----
        float lg[MM];
        float mx = -3.4e38f;
        #pragma unroll
        for (int j = 0; j < MM; ++j) { lg[j] = logit[i * MM + j]; mx = fmaxf(mx, lg[j]); }
        float ssum = 0.f;
        #pragma unroll
        for (int j = 0; j < MM; ++j) { lg[j] = __expf(lg[j] - mx); ssum += lg[j]; }
        const float inv = 1.0f / ssum;
        #pragma unroll
        for (int j = 0; j < MM; ++j) lg[j] *= inv;

        float acc[RPT][W];
        h8 cpin[RPT];
        const bool last = (t == NTERMS - 1);

        // ================= pass 0a: diag + j=9 (d=1) + j=8 (d=2) =============
        {
            float D[W] = {0.f,0.f,0.f,0.f,0.f,0.f,0.f,0.f};
            #pragma unroll
            for (int j = 0; j < MM; ++j) {
                const float4 a = ldq(diag + j * SIZE + s0);
                const float4 b = ldq(diag + j * SIZE + s0 + 4);
                D[0] = fmaf(lg[j], a.x, D[0]); D[1] = fmaf(lg[j], a.y, D[1]);
                D[2] = fmaf(lg[j], a.z, D[2]); D[3] = fmaf(lg[j], a.w, D[3]);
                D[4] = fmaf(lg[j], b.x, D[4]); D[5] = fmaf(lg[j], b.y, D[5]);
                D[6] = fmaf(lg[j], b.z, D[6]); D[7] = fmaf(lg[j], b.w, D[7]);
            }
            float wb9[W], wp9[W], wb8[W], wp8[W];
            ldw8(subpad + 9 * SIZE + s0, lg[9], wb9);
            ldw8(suppad + 9 * SIZE + s0, lg[9], wp9);
            ldw8(subpad + 8 * SIZE + s0, lg[8], wb8);
            ldw8(suppad + 8 * SIZE + s0, lg[8], wp8);

            #pragma unroll
            for (int r = 0; r < RPT; ++r) {
                const _Float16* row = &buf[cur][r0 + r][0];
                const h8 c = *(const h8*)&row[s0];
                const h8 L = *(const h8*)&row[(s0 >= 8)        ? s0 - 8 : 0];
                const h8 R = *(const h8*)&row[(s0 + 8 <= 1016) ? s0 + 8 : 1016];
                cpin[r] = c;
                #pragma unroll
                for (int k = 0; k < W; ++k) acc[r][k] = D[k] * (float)c[k];
                #pragma unroll
                for (int k = 0; k < W; ++k) {          // d=1
                    const float sb = (k >= 1) ? (float)c[k - 1] : (float)L[7];
                    acc[r][k] = fmaf(wb9[k], sb, acc[r][k]);
                    const float sp = (k < 7)  ? (float)c[k + 1] : (float)R[0];
                    acc[r][k] = fmaf(wp9[k], sp, acc[r][k]);
                }
                #pragma unroll
                for (int k = 0; k < W; ++k) {          // d=2
                    const float sb = (k >= 2) ? (float)c[k - 2] : (float)L[6 + k];
                    acc[r][k] = fmaf(wb8[k], sb, acc[r][k]);
                    const float sp = (k < 6)  ? (float)c[k + 2] : (float)R[k - 6];
                    acc[r][k] = fmaf(wp8[k], sp, acc[r][k]);
                }
            }
        }

        // ================= pass 0b: j=7 (d=4) + j=6 (d=8) ====================
        {
            float wb7[W], wp7[W], wb6[W], wp6[W];
            ldw8(subpad + 7 * SIZE + s0, lg[7], wb7);
            ldw8(suppad + 7 * SIZE + s0, lg[7], wp7);
            ldw8(subpad + 6 * SIZE + s0, lg[6], wb6);
            ldw8(suppad + 6 * SIZE + s0, lg[6], wp6);
            #pragma unroll
            for (int r = 0; r < RPT; ++r) {
                const _Float16* row = &buf[cur][r0 + r][0];
                const h8 c = cpin[r];
                const h8 L = *(const h8*)&row[(s0 >= 8)        ? s0 - 8 : 0];
                const h8 R = *(const h8*)&row[(s0 + 8 <= 1016) ? s0 + 8 : 1016];
                #pragma unroll
                for (int k = 0; k < W; ++k) {          // d=4
                    const float sb = (k >= 4) ? (float)c[k - 4] : (float)L[4 + k];
                    acc[r][k] = fmaf(wb7[k], sb, acc[r][k]);
                    const float sp = (k < 4)  ? (float)c[k + 4] : (float)R[k - 4];
                    acc[r][k] = fmaf(wp7[k], sp, acc[r][k]);
                }
                #pragma unroll
                for (int k = 0; k < W; ++k) {          // d=8
                    acc[r][k] = fmaf(wb6[k], (float)L[k], acc[r][k]);
                    acc[r][k] = fmaf(wp6[k], (float)R[k], acc[r][k]);
                }
            }
        }

        // ================= pass 1: far taps j=0..5 (d = 512>>j) ==============
        // ROLLED: keeps only one j's coefs (16 regs) live; p_j recomputed
        // bitwise-identically (same exp + same *inv) to avoid dynamic lg[j].
        #pragma unroll 1
        for (int j = 0; j < 6; ++j) {
            const int d = 512 >> j;
            const float pj = __expf(logit[i * MM + j] - mx) * inv;
            float wb[W], wp[W];
            ldw8(subpad + j * SIZE + s0, pj, wb);
            ldw8(suppad + j * SIZE + s0, pj, wp);
            #pragma unroll
            for (int r = 0; r < RPT; ++r) {
                const _Float16* row = &buf[cur][r0 + r][0];
                const h8 Mm = *(const h8*)&row[(s0 >= d)        ? s0 - d : 0];
                const h8 Pp = *(const h8*)&row[(s0 + d <= 1016) ? s0 + d : 1016];
                #pragma unroll
                for (int k = 0; k < W; ++k) {
                    acc[r][k] = fmaf(wb[k], (float)Mm[k], acc[r][k]);
                    acc[r][k] = fmaf(wp[k], (float)Pp[k], acc[r][k]);
                }
            }
        }

        // ================= writeback ========================================
        if (last) {
            #pragma unroll
            for (int r = 0; r < RPT; ++r) {
                float* op = out + (rowbase + r0 + r) * SIZE + s0;
                *(float4*)op       = make_float4(acc[r][0], acc[r][1], acc[r][2], acc[r][3]);
                *(float4*)(op + 4) = make_float4(acc[r][4], acc[r][5], acc[r][6], acc[r][7]);
            }
        } else {
            #pragma unroll
            for (int r = 0; r < RPT; ++r) {
                h8 hv;
                #pragma unroll
                for (int k = 0; k < W; ++k) hv[k] = (_Float16)acc[r][k];
                *(h8*)&buf[cur ^ 1][r0 + r][s0] = hv;
            }
        }
        __syncthreads();
        cur ^= 1;
    }
}

extern "C" void kernel_launch(void* const* d_in, const int* in_sizes, int n_in,
                              void* d_out, int out_size, void* d_ws, size_t ws_size,
                              hipStream_t stream) {
    const float* x      = (const float*)d_in[0];
    const float* diag   = (const float*)d_in[1];
    const float* subpad = (const float*)d_in[2];
    const float* suppad = (const float*)d_in[3];
    const float* logit  = (const float*)d_in[4];
    float* outp = (float*)d_out;

    const int batch = in_sizes[0] / SIZE;      // 8192
    const int nblocks = batch / RPB;           // 1024

    butterfly_h16<<<dim3(nblocks), dim3(NTHREADS), 0, stream>>>(
        x, diag, subpad, suppad, logit, outp);
}

// Round 4
// 109.441 us; speedup vs baseline: 5.8475x; 5.8475x over previous
//
#include <hip/hip_runtime.h>

#define SIZE 1024
#define MM 10
#define NTERMS 10
#define RPB 8          // batch rows resident per block
#define NTHREADS 256

typedef __attribute__((ext_vector_type(4))) _Float16 h4;   // 8B: ds_read_b64

__device__ __forceinline__ float4 ldq(const float* p) { return *(const float4*)p; }

// a0..a3 live in the enclosing scope; taps v0..v3 are fp32 values
#define FMA4(W, v0, v1, v2, v3)                                      \
    a0 = fmaf((W)[0], (v0), a0); a1 = fmaf((W)[1], (v1), a1);        \
    a2 = fmaf((W)[2], (v2), a2); a3 = fmaf((W)[3], (v3), a3);

// ---------------------------------------------------------------------------
// Round-0 structure EXACTLY (monolithic per-term body, W=4, 84 coef regs,
// compiles to 128 VGPR spill-free at __launch_bounds__(256,2)) with ONE
// change: the inter-term row buffer lives in LDS as fp16, halving DS-pipe
// bytes (ds_read_b64 ~6cyc vs b128 ~12cyc) and halving LDS to 32KB
// (-> 4 blocks/CU). All arithmetic stays fp32 ((float)h casts fold into
// v_fma_mix_f32); only the initial staging + 9 inter-term snapshots round to
// fp16 (RTN). Final term writes fp32 straight to global (no 10th rounding,
// no epilogue). Numerics = round 2/3's verified absmax 0.0625.
// ---------------------------------------------------------------------------
__global__ __launch_bounds__(NTHREADS, 2)
void butterfly_h16(const float* __restrict__ x,
                   const float* __restrict__ diag,
                   const float* __restrict__ subpad,
                   const float* __restrict__ suppad,
                   const float* __restrict__ logit,
                   float* __restrict__ out)
{
    __shared__ _Float16 buf[2][RPB][SIZE];   // 2*8*1024*2B = 32 KB

    const int tid = threadIdx.x;
    const int s0  = tid * 4;              // this thread's quad of s-positions
    const long rowbase = (long)blockIdx.x * RPB;

    // ---- stage this block's 8 rows into LDS (coalesced, fp32->fp16 RTN) ----
    #pragma unroll
    for (int r = 0; r < RPB; ++r) {
        const float4 v = ldq(x + (rowbase + r) * SIZE + s0);
        h4 h;
        h[0] = (_Float16)v.x; h[1] = (_Float16)v.y;
        h[2] = (_Float16)v.z; h[3] = (_Float16)v.w;
        *(h4*)&buf[0][r][s0] = h;
    }
    __syncthreads();

    int cur = 0;
    for (int t = 0; t < NTERMS; ++t) {
        const int i = NTERMS - 1 - t;     // reference applies prob[9] first

        // ---- softmax over logit[i][:] (10 values, redundant per thread) ----
        float lg[MM];
        float mx = -3.4e38f;
        #pragma unroll
        for (int j = 0; j < MM; ++j) { lg[j] = logit[i * MM + j]; mx = fmaxf(mx, lg[j]); }
        float ssum = 0.f;
        #pragma unroll
        for (int j = 0; j < MM; ++j) { lg[j] = __expf(lg[j] - mx); ssum += lg[j]; }
        const float inv = 1.0f / ssum;

        // ---- build prob-weighted coefficients for this thread's quad ----
        float D[4] = {0.f, 0.f, 0.f, 0.f};
        float Wsb[MM][4], Wsp[MM][4];
        #pragma unroll
        for (int j = 0; j < MM; ++j) {
            const float pj = lg[j] * inv;
            const float4 dg = ldq(diag   + j * SIZE + s0);
            const float4 sb = ldq(subpad + j * SIZE + s0);
            const float4 sp = ldq(suppad + j * SIZE + s0);
            D[0] = fmaf(pj, dg.x, D[0]); D[1] = fmaf(pj, dg.y, D[1]);
            D[2] = fmaf(pj, dg.z, D[2]); D[3] = fmaf(pj, dg.w, D[3]);
            Wsb[j][0] = pj * sb.x; Wsb[j][1] = pj * sb.y;
            Wsb[j][2] = pj * sb.z; Wsb[j][3] = pj * sb.w;
            Wsp[j][0] = pj * sp.x; Wsp[j][1] = pj * sp.y;
            Wsp[j][2] = pj * sp.z; Wsp[j][3] = pj * sp.w;
        }

        const bool last = (t == NTERMS - 1);

        // ---- apply the 21-diagonal operator to each resident row ----
        // OOB taps: clamp the LDS address; the matching coefs are exactly 0
        // (subpad zeroed for s<d, suppad zeroed for s>=SIZE-d; s0 and d are
        // multiples of 4 for d>=4, so a clamped quad has ALL-zero coefs;
        // d=1,2 edge lanes pair clamped garbage with zeroed edge coefs).
        for (int r = 0; r < RPB; ++r) {
            const _Float16* row = &buf[cur][r][0];

            const h4 xo = *(const h4*)&row[s0];
            float a0 = D[0] * (float)xo[0], a1 = D[1] * (float)xo[1],
                  a2 = D[2] * (float)xo[2], a3 = D[3] * (float)xo[3];

            const h4 xl = *(const h4*)&row[(s0 >= 4)         ? s0 - 4 : 0];
            const h4 xr = *(const h4*)&row[(s0 + 4 <= 1020)  ? s0 + 4 : 1020];

            // j=9, d=1  (sub: x[s-1], sup: x[s+1])
            FMA4(Wsb[9], (float)xl[3], (float)xo[0], (float)xo[1], (float)xo[2])
            FMA4(Wsp[9], (float)xo[1], (float)xo[2], (float)xo[3], (float)xr[0])
            // j=8, d=2
            FMA4(Wsb[8], (float)xl[2], (float)xl[3], (float)xo[0], (float)xo[1])
            FMA4(Wsp[8], (float)xo[2], (float)xo[3], (float)xr[0], (float)xr[1])
            // j=7, d=4
            FMA4(Wsb[7], (float)xl[0], (float)xl[1], (float)xl[2], (float)xl[3])
            FMA4(Wsp[7], (float)xr[0], (float)xr[1], (float)xr[2], (float)xr[3])
            // j=0..6, d = 512 >> j  (512,256,128,64,32,16,8)
            #pragma unroll
            for (int j = 0; j <= 6; ++j) {
                const int d = 512 >> j;
                const h4 xm = *(const h4*)&row[(s0 >= d)        ? s0 - d : 0];
                const h4 xp = *(const h4*)&row[(s0 + d <= 1020) ? s0 + d : 1020];
                FMA4(Wsb[j], (float)xm[0], (float)xm[1], (float)xm[2], (float)xm[3])
                FMA4(Wsp[j], (float)xp[0], (float)xp[1], (float)xp[2], (float)xp[3])
            }

            if (last) {
                // final term: fp32 result straight to global (coalesced b128)
                *(float4*)(out + (rowbase + r) * SIZE + s0) =
                    make_float4(a0, a1, a2, a3);
            } else {
                h4 hv;
                hv[0] = (_Float16)a0; hv[1] = (_Float16)a1;
                hv[2] = (_Float16)a2; hv[3] = (_Float16)a3;
                *(h4*)&buf[cur ^ 1][r][s0] = hv;
            }
        }
        __syncthreads();   // all writes to buf[cur^1] done before next iter reads
        cur ^= 1;
    }
}

extern "C" void kernel_launch(void* const* d_in, const int* in_sizes, int n_in,
                              void* d_out, int out_size, void* d_ws, size_t ws_size,
                              hipStream_t stream) {
    const float* x      = (const float*)d_in[0];
    const float* diag   = (const float*)d_in[1];
    const float* subpad = (const float*)d_in[2];
    const float* suppad = (const float*)d_in[3];
    const float* logit  = (const float*)d_in[4];
    float* outp = (float*)d_out;

    const int batch = in_sizes[0] / SIZE;      // 8192
    const int nblocks = batch / RPB;           // 1024

    butterfly_h16<<<dim3(nblocks), dim3(NTHREADS), 0, stream>>>(
        x, diag, subpad, suppad, logit, outp);
}